// Round 4
// baseline (457.949 us; speedup 1.0000x reference)
//
#include <hip/hip_runtime.h>

#define NN 4096      // nodes
#define NH 8         // heads
#define BTT 48       // B*T
#define KG 262144    // NN*64 (GEMM K)
#define NJ 512       // 4*Hl
#define HLL 128      // Hl
#define ERAW 65536   // raw edges
#define NKC 256      // GEMM K-split chunks (each 1024)
#define NG  24576    // BTT*NJ

typedef __attribute__((ext_vector_type(8))) short bf16x8;
typedef __attribute__((ext_vector_type(4))) float f32x4;
typedef __attribute__((ext_vector_type(8))) unsigned short ushort8;

typedef __attribute__((address_space(1))) const void* as1_cvp;
typedef __attribute__((address_space(3))) void* as3_vp;

__device__ __forceinline__ unsigned short f2bf(float f) {
  unsigned int u = __float_as_uint(f);
  u += 0x7FFFu + ((u >> 16) & 1u);
  return (unsigned short)(u >> 16);
}
__device__ __forceinline__ float bf2f(unsigned short s) {
  return __uint_as_float(((unsigned int)s) << 16);
}

// ---------------- CSR build: hist + scan + scatter in ONE single-block kernel ----------------
__global__ __launch_bounds__(1024) void k_csr(const int* __restrict__ ei, int* __restrict__ offs,
                                              int* __restrict__ ssrc) {
  __shared__ int cnt[NN];    // counts, then reused as cursors
  __shared__ int ps[1024];
  int t = threadIdx.x;
  for (int i = t; i < NN; i += 1024) cnt[i] = 1;   // self-loop baseline
  __syncthreads();
  for (int e = t; e < ERAW; e += 1024) atomicAdd(&cnt[ei[ERAW + e]], 1);
  __syncthreads();
  int i0 = t * 4;
  int c0 = cnt[i0], c1 = cnt[i0 + 1], c2 = cnt[i0 + 2], c3 = cnt[i0 + 3];
  int s = c0 + c1 + c2 + c3;
  ps[t] = s;
  __syncthreads();
  for (int off = 1; off < 1024; off <<= 1) {
    int v = (t >= off) ? ps[t - off] : 0;
    __syncthreads();
    ps[t] += v;
    __syncthreads();
  }
  int base = ps[t] - s;  // exclusive prefix
  int o0 = base, o1 = o0 + c0, o2 = o1 + c1, o3 = o2 + c2;
  offs[i0] = o0; offs[i0 + 1] = o1; offs[i0 + 2] = o2; offs[i0 + 3] = o3;
  if (t == 1023) offs[NN] = o3 + c3;
  // self-loop occupies slot 0 of each bucket; cursors start at slot 1
  cnt[i0] = o0 + 1; cnt[i0 + 1] = o1 + 1; cnt[i0 + 2] = o2 + 1; cnt[i0 + 3] = o3 + 1;
  ssrc[o0] = i0; ssrc[o1] = i0 + 1; ssrc[o2] = i0 + 2; ssrc[o3] = i0 + 3;
  __syncthreads();
  for (int e = t; e < ERAW; e += 1024) {
    int s2 = ei[e], d = ei[ERAW + e];
    int pos = atomicAdd(&cnt[d], 1);
    ssrc[pos] = s2;
  }
}

// ---------------- projection + attention logits (h stored bf16) ----------------
__global__ __launch_bounds__(256) void k_proj(const float* __restrict__ x, const float* __restrict__ Wg,
                                              const float* __restrict__ att_s, const float* __restrict__ att_d,
                                              unsigned short* __restrict__ h, float* __restrict__ a_s,
                                              float* __restrict__ a_d) {
  __shared__ float wgs[512];
  __shared__ float ats[64], atd[64];
  int tid = threadIdx.x;
  wgs[tid] = Wg[tid];
  wgs[256 + tid] = Wg[256 + tid];
  if (tid < 64) { ats[tid] = att_s[tid]; atd[tid] = att_d[tid]; }
  __syncthreads();
  int bt = blockIdx.x >> 7;
  int inner = blockIdx.x & 127;
  int hd = tid & 7, nl = tid >> 3;
  int n = inner * 32 + nl;
  const float* xr = x + ((size_t)(bt * NN + n)) * 8;
  float4 xa = *(const float4*)xr, xb2 = *(const float4*)(xr + 4);
  float xv[8] = {xa.x, xa.y, xa.z, xa.w, xb2.x, xb2.y, xb2.z, xb2.w};
  int hb = hd * 8;
  float hv[8];
#pragma unroll
  for (int c = 0; c < 8; ++c) {
    float acc = 0.f;
#pragma unroll
    for (int f = 0; f < 8; ++f) acc += xv[f] * wgs[f * 64 + hb + c];
    hv[c] = acc;
  }
  float as = 0.f, ad = 0.f;
#pragma unroll
  for (int c = 0; c < 8; ++c) { as += hv[c] * ats[hb + c]; ad += hv[c] * atd[hb + c]; }
  int aoff = bt * (NN * NH) + n * NH + hd;
  a_s[aoff] = as;
  a_d[aoff] = ad;
  ushort8 hr;
#pragma unroll
  for (int c = 0; c < 8; ++c) hr[c] = f2bf(hv[c]);
  *(ushort8*)(h + (size_t)bt * KG + (size_t)n * 64 + hb) = hr;
}

// ---------------- GAT aggregation (online softmax over CSR bucket) ----------------
__global__ __launch_bounds__(256) void k_gat(const unsigned short* __restrict__ h, const float* __restrict__ a_s,
                                             const float* __restrict__ a_d, const int* __restrict__ offs,
                                             const int* __restrict__ ssrc, const float* __restrict__ b_gat,
                                             unsigned short* __restrict__ Xb) {
  int bt = blockIdx.x >> 7;
  int inner = blockIdx.x & 127;
  int tid = threadIdx.x;
  int hd = tid & 7, nl = tid >> 3;
  int n = inner * 32 + nl;
  const unsigned short* hbase = h + (size_t)bt * KG;
  const float* asb = a_s + bt * (NN * NH);
  float adn = a_d[bt * (NN * NH) + n * NH + hd];
  int beg = offs[n], end = offs[n + 1];
  float m = -INFINITY, ssum = 0.f;
  float o[8];
#pragma unroll
  for (int c = 0; c < 8; ++c) o[c] = 0.f;
  for (int i = beg; i < end; ++i) {
    int s = ssrc[i];
    float e = asb[s * NH + hd] + adn;
    e = (e > 0.f) ? e : 0.2f * e;  // leaky_relu(0.2)
    if (e > m) {
      float r = __expf(m - e);     // first iter: exp(-inf)=0
      ssum *= r;
#pragma unroll
      for (int c = 0; c < 8; ++c) o[c] *= r;
      m = e;
    }
    float p = __expf(e - m);
    ssum += p;
    ushort8 hvv = *(const ushort8*)(hbase + (size_t)s * 64 + hd * 8);
#pragma unroll
    for (int c = 0; c < 8; ++c) o[c] += p * bf2f(hvv[c]);
  }
  float inv = 1.f / ssum;
  ushort8 r;
#pragma unroll
  for (int c = 0; c < 8; ++c) {
    float v = o[c] * inv + b_gat[hd * 8 + c];
    v = (v > 0.f) ? v : (__expf(v) - 1.f);  // ELU
    r[c] = f2bf(v);
  }
  *(ushort8*)(Xb + (size_t)bt * KG + (size_t)n * 64 + hd * 8) = r;
}

// ---------------- big skinny GEMM: Gp[kc][48][512] = X[48,Kc] * Wih[512,Kc]^T ----------------
// Wave-private 3-deep gl_lds pipeline, counted vmcnt (never 0 mid-loop), NO barriers.
// Fixed 7-op issue group per tile: 3x X->reg, 4x W->LDS(16B). Swizzle pair verified in R2.
#define WAITVM(n) asm volatile("s_waitcnt vmcnt(" #n ")" ::: "memory")

#define GRP(sl, tt) do {                                                          \
    int off_ = (tt) * 32;                                                         \
    xb_[sl][0] = *(const bf16x8*)(xr0 + off_);                                    \
    xb_[sl][1] = *(const bf16x8*)(xr1 + off_);                                    \
    xb_[sl][2] = *(const bf16x8*)(xr2 + off_);                                    \
    _Pragma("unroll")                                                             \
    for (int i_ = 0; i_ < 4; ++i_)                                                \
      __builtin_amdgcn_global_load_lds((as1_cvp)(sbase[i_] + off_),               \
          (as3_vp)(wlds + (sl) * 16384 + (w * 4 + i_) * 1024), 16, 0, 0);         \
  } while (0)

#define CONS(sl) do {                                                             \
    const char* tile_ = wlds + (sl) * 16384;                                      \
    _Pragma("unroll")                                                             \
    for (int jf = 0; jf < 2; ++jf) {                                              \
      int row_ = w * 32 + jf * 16 + lm;                                           \
      int A0_ = row_ * 128 + ((kg * 32) ^ ((row_ & 7) << 4));                     \
      float4 f0 = *(const float4*)(tile_ + A0_);                                  \
      float4 f1 = *(const float4*)(tile_ + (A0_ ^ 16));                           \
      bf16x8 bfr;                                                                 \
      bfr[0] = (short)f2bf(f0.x); bfr[1] = (short)f2bf(f0.y);                     \
      bfr[2] = (short)f2bf(f0.z); bfr[3] = (short)f2bf(f0.w);                     \
      bfr[4] = (short)f2bf(f1.x); bfr[5] = (short)f2bf(f1.y);                     \
      bfr[6] = (short)f2bf(f1.z); bfr[7] = (short)f2bf(f1.w);                     \
      acc[0][jf] = __builtin_amdgcn_mfma_f32_16x16x32_bf16(xb_[sl][0], bfr, acc[0][jf], 0, 0, 0); \
      acc[1][jf] = __builtin_amdgcn_mfma_f32_16x16x32_bf16(xb_[sl][1], bfr, acc[1][jf], 0, 0, 0); \
      acc[2][jf] = __builtin_amdgcn_mfma_f32_16x16x32_bf16(xb_[sl][2], bfr, acc[2][jf], 0, 0, 0); \
    }                                                                             \
  } while (0)

__global__ __launch_bounds__(256) void k_gemm(const unsigned short* __restrict__ Xb,
                                              const float* __restrict__ Wih, float* __restrict__ Gp) {
  __shared__ float Wt[3][4096];  // 3 x 16KB rotating W buffers (swizzled layout)
  char* wlds = (char*)&Wt[0][0];
  int tid = threadIdx.x;
  int w = tid >> 6, lane = tid & 63;
  int lm = lane & 15, kg = lane >> 4;
  int jb = blockIdx.x & 3;       // 4 j-blocks of 128
  int kc = blockIdx.x >> 2;      // 256 k-chunks of 1024
  size_t kbase = (size_t)kc * 1024;

  // staging sources (pre-swizzled columns). Wave w stages exactly rows w*32..w*32+31,
  // which are exactly the rows it consumes -> no cross-wave dependency, no barriers.
  const float* sbase[4];
#pragma unroll
  for (int i = 0; i < 4; ++i) {
    int row = ((w * 4 + i) << 3) + (lane >> 3);
    int colf = ((lane & 7) ^ (row & 7)) << 2;
    sbase[i] = Wih + (size_t)(jb * 128 + row) * KG + kbase + colf;
  }
  const short* Xs = (const short*)Xb;
  const short* xr0 = Xs + (size_t)lm * KG + kbase + kg * 8;
  const short* xr1 = xr0 + (size_t)16 * KG;
  const short* xr2 = xr0 + (size_t)32 * KG;

  f32x4 acc[3][2];
#pragma unroll
  for (int mf = 0; mf < 3; ++mf)
#pragma unroll
    for (int jf = 0; jf < 2; ++jf) acc[mf][jf] = f32x4{0.f, 0.f, 0.f, 0.f};

  bf16x8 xb_[3][3];  // [slot][mf] — all indices compile-time constant

  GRP(0, 0);
  GRP(1, 1);
  for (int tb = 0; tb < 30; tb += 3) {
    GRP(2, tb + 2); WAITVM(14); __builtin_amdgcn_sched_barrier(0); CONS(0);
    GRP(0, tb + 3); WAITVM(14); __builtin_amdgcn_sched_barrier(0); CONS(1);
    GRP(1, tb + 4); WAITVM(14); __builtin_amdgcn_sched_barrier(0); CONS(2);
  }
  WAITVM(7);  __builtin_amdgcn_sched_barrier(0); CONS(0);  // tile 30
  WAITVM(0);  __builtin_amdgcn_sched_barrier(0); CONS(1);  // tile 31

  // epilogue: non-atomic partials Gp[kc][bt][j]
  float* gout = Gp + (size_t)kc * NG;
#pragma unroll
  for (int mf = 0; mf < 3; ++mf)
#pragma unroll
    for (int jf = 0; jf < 2; ++jf) {
      int j = jb * 128 + w * 32 + jf * 16 + lm;
#pragma unroll
      for (int r = 0; r < 4; ++r) {
        int bt = mf * 16 + kg * 4 + r;   // C/D: col=lane&15, row=(lane>>4)*4+r
        gout[bt * NJ + j] = acc[mf][jf][r];
      }
    }
}

// ---------------- reduce partials stage 1: Gp2[s][.] = sum of 32 chunks ----------------
__global__ __launch_bounds__(256) void k_red1(const float* __restrict__ Gp, float* __restrict__ Gp2) {
  int idx = blockIdx.x * 256 + threadIdx.x;   // 196608 threads = 8 segs x 24576
  int seg = idx / NG;
  int gid = idx - seg * NG;
  const float* src = Gp + (size_t)seg * 32 * NG + gid;
  float acc = 0.f;
#pragma unroll 8
  for (int i = 0; i < 32; ++i) acc += src[(size_t)i * NG];
  Gp2[idx] = acc;
}

// ---------------- LSTM (one block per batch element; folds reduce stage 2) ----------------
__global__ __launch_bounds__(512) void k_lstm(const float* __restrict__ Gp2, const float* __restrict__ Whh,
                                              const float* __restrict__ bih, const float* __restrict__ bhh,
                                              float* __restrict__ hlast) {
  __shared__ float hs[HLL];
  __shared__ float gs[NJ];
  int b = blockIdx.x, j = threadIdx.x;
  float bias = bih[j] + bhh[j];
  float w[HLL];
  const float* wr = Whh + (size_t)j * HLL;
#pragma unroll
  for (int k = 0; k < HLL; k += 4) {
    float4 v = *(const float4*)(wr + k);
    w[k] = v.x; w[k + 1] = v.y; w[k + 2] = v.z; w[k + 3] = v.w;
  }
  if (j < HLL) hs[j] = 0.f;
  float c = 0.f;
  __syncthreads();
  for (int t = 0; t < 12; ++t) {
    const float* gp = Gp2 + (size_t)(b * 12 + t) * NJ + j;
    float acc = bias;
#pragma unroll
    for (int s = 0; s < 8; ++s) acc += gp[(size_t)s * NG];   // fold reduce stage 2
#pragma unroll
    for (int k = 0; k < HLL; ++k) acc += w[k] * hs[k];
    gs[j] = acc;
    __syncthreads();
    if (j < HLL) {
      float gi = gs[j], gf = gs[HLL + j], gg = gs[2 * HLL + j], go = gs[3 * HLL + j];
      float si = 1.f / (1.f + __expf(-gi));
      float sf = 1.f / (1.f + __expf(-gf));
      float so = 1.f / (1.f + __expf(-go));
      c = sf * c + si * tanhf(gg);
      hs[j] = so * tanhf(c);
    }
    __syncthreads();
  }
  if (j < HLL) hlast[b * HLL + j] = hs[j];
}

// ---------------- FC epilogue ----------------
__global__ __launch_bounds__(256) void k_fc(const float* __restrict__ hlast, const float* __restrict__ Wfc,
                                            const float* __restrict__ bfc, float* __restrict__ out) {
  __shared__ float hl[NJ];
  int tid = threadIdx.x;
  hl[tid] = hlast[tid];
  hl[256 + tid] = hlast[256 + tid];
  __syncthreads();
  int n = blockIdx.x * 256 + tid;
  float a0 = 0.f, a1 = 0.f, a2 = 0.f, a3 = 0.f;
#pragma unroll 8
  for (int k = 0; k < HLL; ++k) {
    float wv = Wfc[(size_t)k * 32768 + n];
    a0 += hl[k] * wv;
    a1 += hl[HLL + k] * wv;
    a2 += hl[2 * HLL + k] * wv;
    a3 += hl[3 * HLL + k] * wv;
  }
  float bb = bfc[n];
  out[n] = a0 + bb;
  out[32768 + n] = a1 + bb;
  out[65536 + n] = a2 + bb;
  out[98304 + n] = a3 + bb;
}

extern "C" void kernel_launch(void* const* d_in, const int* in_sizes, int n_in,
                              void* d_out, int out_size, void* d_ws, size_t ws_size,
                              hipStream_t stream) {
  const float* x     = (const float*)d_in[0];
  const int*   ei    = (const int*)d_in[1];   // int32 (JAX x64 off)
  const float* Wg    = (const float*)d_in[2];
  const float* att_s = (const float*)d_in[3];
  const float* att_d = (const float*)d_in[4];
  const float* b_gat = (const float*)d_in[5];
  const float* Wih   = (const float*)d_in[6];
  const float* Whh   = (const float*)d_in[7];
  const float* bih   = (const float*)d_in[8];
  const float* bhh   = (const float*)d_in[9];
  const float* Wfc   = (const float*)d_in[10];
  const float* bfc   = (const float*)d_in[11];
  float* out = (float*)d_out;

  char* ws = (char*)d_ws;
  unsigned short* h  = (unsigned short*)(ws);      // bf16: 48*4096*64*2 = 25165824
  float* a_s         = (float*)(ws + 25165824);    // 48*4096*8*4       =  6291456
  float* a_d         = (float*)(ws + 31457280);    //                      6291456
  unsigned short* Xb = (unsigned short*)(ws + 37748736); // bf16        = 25165824
  float* Gp          = (float*)(ws + 62914560);    // 256*48*512*4      = 25165824
  float* Gp2         = (float*)(ws + 88080384);    // 8*24576*4         =   786432
  float* hlast       = (float*)(ws + 88866816);    // 512*4
  int* offs          = (int*)(ws + 88868864);      // 4097*4
  int* ssrc          = (int*)(ws + 88885256);      // 69632*4

  hipLaunchKernelGGL(k_csr,  dim3(1),        dim3(1024), 0, stream, ei, offs, ssrc);
  hipLaunchKernelGGL(k_proj, dim3(48 * 128), dim3(256),  0, stream, x, Wg, att_s, att_d, h, a_s, a_d);
  hipLaunchKernelGGL(k_gat,  dim3(48 * 128), dim3(256),  0, stream, h, a_s, a_d, offs, ssrc, b_gat, Xb);
  hipLaunchKernelGGL(k_gemm, dim3(1024),     dim3(256),  0, stream, Xb, Wih, Gp);
  hipLaunchKernelGGL(k_red1, dim3(768),      dim3(256),  0, stream, Gp, Gp2);
  hipLaunchKernelGGL(k_lstm, dim3(4),        dim3(512),  0, stream, Gp2, Whh, bih, bhh, hlast);
  hipLaunchKernelGGL(k_fc,   dim3(128),      dim3(256),  0, stream, hlast, Wfc, bfc, out);
}

// Round 5
// 314.864 us; speedup vs baseline: 1.4544x; 1.4544x over previous
//
#include <hip/hip_runtime.h>

#define NN 4096      // nodes
#define NH 8         // heads
#define BTT 48       // B*T
#define KG 262144    // NN*64 (GEMM K)
#define NJ 512       // 4*Hl
#define HLL 128      // Hl
#define ERAW 65536   // raw edges
#define NKC 256      // GEMM K-split chunks (each 1024)
#define NG  24576    // BTT*NJ

typedef __attribute__((ext_vector_type(8))) short bf16x8;
typedef __attribute__((ext_vector_type(4))) float f32x4;
typedef __attribute__((ext_vector_type(8))) unsigned short ushort8;

__device__ __forceinline__ unsigned short f2bf(float f) {
  unsigned int u = __float_as_uint(f);
  u += 0x7FFFu + ((u >> 16) & 1u);
  return (unsigned short)(u >> 16);
}
__device__ __forceinline__ float bf2f(unsigned short s) {
  return __uint_as_float(((unsigned int)s) << 16);
}

// ---------------- CSR build (4 small parallel kernels — R4's single-block fusion regressed) ----------------
__global__ __launch_bounds__(256) void k_init(int* __restrict__ counts) {
  int t = blockIdx.x * 256 + threadIdx.x;
  counts[t] = 1;                                    // self-loop baseline
}

__global__ __launch_bounds__(256) void k_hist(const int* __restrict__ ei, int* __restrict__ counts) {
  int e = blockIdx.x * 256 + threadIdx.x;
  atomicAdd(&counts[ei[ERAW + e]], 1);
}

__global__ __launch_bounds__(1024) void k_scan(const int* __restrict__ counts, int* __restrict__ offs,
                                               int* __restrict__ cursor, int* __restrict__ ssrc) {
  __shared__ int p[1024];
  int t = threadIdx.x;
  int i0 = t * 4;
  int c0 = counts[i0], c1 = counts[i0 + 1], c2 = counts[i0 + 2], c3 = counts[i0 + 3];
  int s = c0 + c1 + c2 + c3;
  p[t] = s;
  __syncthreads();
  for (int off = 1; off < 1024; off <<= 1) {
    int v = (t >= off) ? p[t - off] : 0;
    __syncthreads();
    p[t] += v;
    __syncthreads();
  }
  int base = p[t] - s;  // exclusive prefix
  int o0 = base, o1 = o0 + c0, o2 = o1 + c1, o3 = o2 + c2;
  offs[i0] = o0; offs[i0 + 1] = o1; offs[i0 + 2] = o2; offs[i0 + 3] = o3;
  if (t == 1023) offs[NN] = o3 + c3;
  cursor[i0] = o0 + 1; cursor[i0 + 1] = o1 + 1; cursor[i0 + 2] = o2 + 1; cursor[i0 + 3] = o3 + 1;
  // self-loop occupies slot 0 of each bucket
  ssrc[o0] = i0; ssrc[o1] = i0 + 1; ssrc[o2] = i0 + 2; ssrc[o3] = i0 + 3;
}

__global__ __launch_bounds__(256) void k_scatter(const int* __restrict__ ei, int* __restrict__ cursor,
                                                 int* __restrict__ ssrc) {
  int e = blockIdx.x * 256 + threadIdx.x;
  int s = ei[e], d = ei[ERAW + e];
  int pos = atomicAdd(&cursor[d], 1);
  ssrc[pos] = s;
}

// ---------------- projection + attention logits (h stored bf16) ----------------
__global__ __launch_bounds__(256) void k_proj(const float* __restrict__ x, const float* __restrict__ Wg,
                                              const float* __restrict__ att_s, const float* __restrict__ att_d,
                                              unsigned short* __restrict__ h, float* __restrict__ a_s,
                                              float* __restrict__ a_d) {
  __shared__ float wgs[512];
  __shared__ float ats[64], atd[64];
  int tid = threadIdx.x;
  wgs[tid] = Wg[tid];
  wgs[256 + tid] = Wg[256 + tid];
  if (tid < 64) { ats[tid] = att_s[tid]; atd[tid] = att_d[tid]; }
  __syncthreads();
  int bt = blockIdx.x >> 7;
  int inner = blockIdx.x & 127;
  int hd = tid & 7, nl = tid >> 3;
  int n = inner * 32 + nl;
  const float* xr = x + ((size_t)(bt * NN + n)) * 8;
  float4 xa = *(const float4*)xr, xb2 = *(const float4*)(xr + 4);
  float xv[8] = {xa.x, xa.y, xa.z, xa.w, xb2.x, xb2.y, xb2.z, xb2.w};
  int hb = hd * 8;
  float hv[8];
#pragma unroll
  for (int c = 0; c < 8; ++c) {
    float acc = 0.f;
#pragma unroll
    for (int f = 0; f < 8; ++f) acc += xv[f] * wgs[f * 64 + hb + c];
    hv[c] = acc;
  }
  float as = 0.f, ad = 0.f;
#pragma unroll
  for (int c = 0; c < 8; ++c) { as += hv[c] * ats[hb + c]; ad += hv[c] * atd[hb + c]; }
  int aoff = bt * (NN * NH) + n * NH + hd;
  a_s[aoff] = as;
  a_d[aoff] = ad;
  ushort8 hr;
#pragma unroll
  for (int c = 0; c < 8; ++c) hr[c] = f2bf(hv[c]);
  *(ushort8*)(h + (size_t)bt * KG + (size_t)n * 64 + hb) = hr;
}

// ---------------- GAT aggregation, bt->XCD pinned (L2-capacity fix) ----------------
// All 128 blocks of one bt share blockIdx%8 -> same XCD (round-robin dispatch) -> the
// bt's 640KB gather set (h + a_s) stays L2-resident instead of 16 bts thrashing 4MiB.
__global__ __launch_bounds__(256) void k_gat(const unsigned short* __restrict__ h, const float* __restrict__ a_s,
                                             const float* __restrict__ a_d, const int* __restrict__ offs,
                                             const int* __restrict__ ssrc, const float* __restrict__ b_gat,
                                             unsigned short* __restrict__ Xb) {
  int B = blockIdx.x;
  int xcd = B & 7;
  int slot = B >> 3;            // 0..767
  int btg = slot >> 7;          // 0..5
  int inner = slot & 127;       // 0..127
  int bt = btg * 8 + xcd;       // all 128 blocks of bt share B&7
  int tid = threadIdx.x;
  int hd = tid & 7, nl = tid >> 3;
  int n = inner * 32 + nl;
  const unsigned short* hbase = h + (size_t)bt * KG;
  const float* asb = a_s + bt * (NN * NH);
  float adn = a_d[bt * (NN * NH) + n * NH + hd];
  int beg = offs[n], end = offs[n + 1];
  float m = -INFINITY, ssum = 0.f;
  float o[8];
#pragma unroll
  for (int c = 0; c < 8; ++c) o[c] = 0.f;
  for (int i = beg; i < end; ++i) {
    int s = ssrc[i];
    float e = asb[s * NH + hd] + adn;
    e = (e > 0.f) ? e : 0.2f * e;  // leaky_relu(0.2)
    if (e > m) {
      float r = __expf(m - e);     // first iter: exp(-inf)=0
      ssum *= r;
#pragma unroll
      for (int c = 0; c < 8; ++c) o[c] *= r;
      m = e;
    }
    float p = __expf(e - m);
    ssum += p;
    ushort8 hvv = *(const ushort8*)(hbase + (size_t)s * 64 + hd * 8);
#pragma unroll
    for (int c = 0; c < 8; ++c) o[c] += p * bf2f(hvv[c]);
  }
  float inv = 1.f / ssum;
  ushort8 r;
#pragma unroll
  for (int c = 0; c < 8; ++c) {
    float v = o[c] * inv + b_gat[hd * 8 + c];
    v = (v > 0.f) ? v : (__expf(v) - 1.f);  // ELU
    r[c] = f2bf(v);
  }
  *(ushort8*)(Xb + (size_t)bt * KG + (size_t)n * 64 + hd * 8) = r;
}

// ---------------- big skinny GEMM: Gp[kc][48][512] = X[48,Kc] * Wih[512,Kc]^T ----------------
// Register double-buffered streaming (R3 version — best measured so far).
__global__ __launch_bounds__(256) void k_gemm(const unsigned short* __restrict__ Xb,
                                              const float* __restrict__ Wih, float* __restrict__ Gp) {
  int tid = threadIdx.x;
  int w = tid >> 6, lane = tid & 63;
  int lm = lane & 15, kg = lane >> 4;
  int jb = blockIdx.x & 3;       // 4 j-blocks of 128
  int kc = blockIdx.x >> 2;      // 256 k-chunks of 1024
  int j0 = jb * 128 + w * 32;    // this wave's 32 W-rows
  size_t kbase = (size_t)kc * 1024 + kg * 8;

  const float* wr0 = Wih + (size_t)(j0 + lm) * KG + kbase;        // jf=0 rows
  const float* wr1 = Wih + (size_t)(j0 + 16 + lm) * KG + kbase;   // jf=1 rows
  const short* Xs = (const short*)Xb;
  const short* xr0 = Xs + (size_t)lm * KG + kbase;
  const short* xr1 = xr0 + (size_t)16 * KG;
  const short* xr2 = xr0 + (size_t)32 * KG;

  f32x4 acc[3][2];
#pragma unroll
  for (int mf = 0; mf < 3; ++mf)
#pragma unroll
    for (int jf = 0; jf < 2; ++jf) acc[mf][jf] = f32x4{0.f, 0.f, 0.f, 0.f};

  float4 wbuf[2][4];   // [buf][jf*2+half]
  bf16x8 abuf[2][3];   // [buf][mf]

  wbuf[0][0] = *(const float4*)(wr0);
  wbuf[0][1] = *(const float4*)(wr0 + 4);
  wbuf[0][2] = *(const float4*)(wr1);
  wbuf[0][3] = *(const float4*)(wr1 + 4);
  abuf[0][0] = *(const bf16x8*)(xr0);
  abuf[0][1] = *(const bf16x8*)(xr1);
  abuf[0][2] = *(const bf16x8*)(xr2);

#pragma unroll 2
  for (int t = 0; t < 32; ++t) {
    int cur = t & 1, nxt = cur ^ 1;
    if (t + 1 < 32) {
      int off = (t + 1) * 32;
      wbuf[nxt][0] = *(const float4*)(wr0 + off);
      wbuf[nxt][1] = *(const float4*)(wr0 + off + 4);
      wbuf[nxt][2] = *(const float4*)(wr1 + off);
      wbuf[nxt][3] = *(const float4*)(wr1 + off + 4);
      abuf[nxt][0] = *(const bf16x8*)(xr0 + off);
      abuf[nxt][1] = *(const bf16x8*)(xr1 + off);
      abuf[nxt][2] = *(const bf16x8*)(xr2 + off);
    }
#pragma unroll
    for (int jf = 0; jf < 2; ++jf) {
      float4 f0 = wbuf[cur][jf * 2], f1 = wbuf[cur][jf * 2 + 1];
      bf16x8 b;
      b[0] = (short)f2bf(f0.x); b[1] = (short)f2bf(f0.y);
      b[2] = (short)f2bf(f0.z); b[3] = (short)f2bf(f0.w);
      b[4] = (short)f2bf(f1.x); b[5] = (short)f2bf(f1.y);
      b[6] = (short)f2bf(f1.z); b[7] = (short)f2bf(f1.w);
      acc[0][jf] = __builtin_amdgcn_mfma_f32_16x16x32_bf16(abuf[cur][0], b, acc[0][jf], 0, 0, 0);
      acc[1][jf] = __builtin_amdgcn_mfma_f32_16x16x32_bf16(abuf[cur][1], b, acc[1][jf], 0, 0, 0);
      acc[2][jf] = __builtin_amdgcn_mfma_f32_16x16x32_bf16(abuf[cur][2], b, acc[2][jf], 0, 0, 0);
    }
  }

  // epilogue: non-atomic partials Gp[kc][bt][j]
  float* gout = Gp + (size_t)kc * NG;
#pragma unroll
  for (int mf = 0; mf < 3; ++mf)
#pragma unroll
    for (int jf = 0; jf < 2; ++jf) {
      int j = j0 + jf * 16 + lm;
#pragma unroll
      for (int r = 0; r < 4; ++r) {
        int bt = mf * 16 + kg * 4 + r;   // C/D: col=lane&15, row=(lane>>4)*4+r
        gout[bt * NJ + j] = acc[mf][jf][r];
      }
    }
}

// ---------------- reduce partials stage 1: Gp2[s][.] = sum of 32 chunks ----------------
__global__ __launch_bounds__(256) void k_red1(const float* __restrict__ Gp, float* __restrict__ Gp2) {
  int idx = blockIdx.x * 256 + threadIdx.x;   // 196608 threads = 8 segs x 24576
  int seg = idx / NG;
  int gid = idx - seg * NG;
  const float* src = Gp + (size_t)seg * 32 * NG + gid;
  float acc = 0.f;
#pragma unroll 8
  for (int i = 0; i < 32; ++i) acc += src[(size_t)i * NG];
  Gp2[idx] = acc;
}

// ---------------- LSTM (one block per batch element; folds reduce stage 2) ----------------
__global__ __launch_bounds__(512) void k_lstm(const float* __restrict__ Gp2, const float* __restrict__ Whh,
                                              const float* __restrict__ bih, const float* __restrict__ bhh,
                                              float* __restrict__ hlast) {
  __shared__ float hs[HLL];
  __shared__ float gs[NJ];
  int b = blockIdx.x, j = threadIdx.x;
  float bias = bih[j] + bhh[j];
  float w[HLL];
  const float* wr = Whh + (size_t)j * HLL;
#pragma unroll
  for (int k = 0; k < HLL; k += 4) {
    float4 v = *(const float4*)(wr + k);
    w[k] = v.x; w[k + 1] = v.y; w[k + 2] = v.z; w[k + 3] = v.w;
  }
  if (j < HLL) hs[j] = 0.f;
  float c = 0.f;
  __syncthreads();
  for (int t = 0; t < 12; ++t) {
    const float* gp = Gp2 + (size_t)(b * 12 + t) * NJ + j;
    float acc = bias;
#pragma unroll
    for (int s = 0; s < 8; ++s) acc += gp[(size_t)s * NG];   // fold reduce stage 2
#pragma unroll
    for (int k = 0; k < HLL; ++k) acc += w[k] * hs[k];
    gs[j] = acc;
    __syncthreads();
    if (j < HLL) {
      float gi = gs[j], gf = gs[HLL + j], gg = gs[2 * HLL + j], go = gs[3 * HLL + j];
      float si = 1.f / (1.f + __expf(-gi));
      float sf = 1.f / (1.f + __expf(-gf));
      float so = 1.f / (1.f + __expf(-go));
      c = sf * c + si * tanhf(gg);
      hs[j] = so * tanhf(c);
    }
    __syncthreads();
  }
  if (j < HLL) hlast[b * HLL + j] = hs[j];
}

// ---------------- FC epilogue ----------------
__global__ __launch_bounds__(256) void k_fc(const float* __restrict__ hlast, const float* __restrict__ Wfc,
                                            const float* __restrict__ bfc, float* __restrict__ out) {
  __shared__ float hl[NJ];
  int tid = threadIdx.x;
  hl[tid] = hlast[tid];
  hl[256 + tid] = hlast[256 + tid];
  __syncthreads();
  int n = blockIdx.x * 256 + tid;
  float a0 = 0.f, a1 = 0.f, a2 = 0.f, a3 = 0.f;
#pragma unroll 8
  for (int k = 0; k < HLL; ++k) {
    float wv = Wfc[(size_t)k * 32768 + n];
    a0 += hl[k] * wv;
    a1 += hl[HLL + k] * wv;
    a2 += hl[2 * HLL + k] * wv;
    a3 += hl[3 * HLL + k] * wv;
  }
  float bb = bfc[n];
  out[n] = a0 + bb;
  out[32768 + n] = a1 + bb;
  out[65536 + n] = a2 + bb;
  out[98304 + n] = a3 + bb;
}

extern "C" void kernel_launch(void* const* d_in, const int* in_sizes, int n_in,
                              void* d_out, int out_size, void* d_ws, size_t ws_size,
                              hipStream_t stream) {
  const float* x     = (const float*)d_in[0];
  const int*   ei    = (const int*)d_in[1];   // int32 (JAX x64 off)
  const float* Wg    = (const float*)d_in[2];
  const float* att_s = (const float*)d_in[3];
  const float* att_d = (const float*)d_in[4];
  const float* b_gat = (const float*)d_in[5];
  const float* Wih   = (const float*)d_in[6];
  const float* Whh   = (const float*)d_in[7];
  const float* bih   = (const float*)d_in[8];
  const float* bhh   = (const float*)d_in[9];
  const float* Wfc   = (const float*)d_in[10];
  const float* bfc   = (const float*)d_in[11];
  float* out = (float*)d_out;

  char* ws = (char*)d_ws;
  unsigned short* h  = (unsigned short*)(ws);      // bf16: 48*4096*64*2 = 25165824
  float* a_s         = (float*)(ws + 25165824);    // 48*4096*8*4       =  6291456
  float* a_d         = (float*)(ws + 31457280);    //                      6291456
  unsigned short* Xb = (unsigned short*)(ws + 37748736); // bf16        = 25165824
  float* Gp          = (float*)(ws + 62914560);    // 256*48*512*4      = 25165824
  float* Gp2         = (float*)(ws + 88080384);    // 8*24576*4         =   786432
  float* hlast       = (float*)(ws + 88866816);    // 512*4
  int* counts        = (int*)(ws + 88868864);      // 4096*4
  int* offs          = (int*)(ws + 88885248);      // 4097*4
  int* cursor        = (int*)(ws + 88901644);      // 4096*4 (4-byte aligned ok)
  int* ssrc          = (int*)(ws + 88918028);      // 69632*4

  hipLaunchKernelGGL(k_init,    dim3(16),       dim3(256),  0, stream, counts);
  hipLaunchKernelGGL(k_hist,    dim3(256),      dim3(256),  0, stream, ei, counts);
  hipLaunchKernelGGL(k_scan,    dim3(1),        dim3(1024), 0, stream, counts, offs, cursor, ssrc);
  hipLaunchKernelGGL(k_scatter, dim3(256),      dim3(256),  0, stream, ei, cursor, ssrc);
  hipLaunchKernelGGL(k_proj,    dim3(48 * 128), dim3(256),  0, stream, x, Wg, att_s, att_d, h, a_s, a_d);
  hipLaunchKernelGGL(k_gat,     dim3(48 * 128), dim3(256),  0, stream, h, a_s, a_d, offs, ssrc, b_gat, Xb);
  hipLaunchKernelGGL(k_gemm,    dim3(1024),     dim3(256),  0, stream, Xb, Wih, Gp);
  hipLaunchKernelGGL(k_red1,    dim3(768),      dim3(256),  0, stream, Gp, Gp2);
  hipLaunchKernelGGL(k_lstm,    dim3(4),        dim3(512),  0, stream, Gp2, Whh, bih, bhh, hlast);
  hipLaunchKernelGGL(k_fc,      dim3(128),      dim3(256),  0, stream, hlast, Wfc, bfc, out);
}